// Round 7
// baseline (1821.363 us; speedup 1.0000x reference)
//
#include <hip/hip_runtime.h>
#include <math.h>
#include <stdint.h>

#define EMBS 32
#define INS 64
#define HS 128
#define OUTS 256
#define BS 64
#define SS 2048

typedef _Float16 half2v __attribute__((ext_vector_type(2)));
typedef _Float16 half8 __attribute__((ext_vector_type(8)));
typedef float f32x4 __attribute__((ext_vector_type(4)));

// ws layout (4B elems): emb [B][S][IN] f32 | dist [B][IN] f32 | hfin [B][H] f32 | xw [B][S][256] half2v
static constexpr size_t WS_DIST  = (size_t)BS * SS * INS;
static constexpr size_t WS_HFIN  = WS_DIST + (size_t)BS * INS;
static constexpr size_t WS_XW    = WS_HFIN + (size_t)BS * HS;
static constexpr size_t WS_SMALL = WS_XW;
static constexpr size_t WS_BIG   = WS_XW + (size_t)BS * SS * 256;

__device__ __forceinline__ float fexp2(float x) {
#if __has_builtin(__builtin_amdgcn_exp2f)
    return __builtin_amdgcn_exp2f(x);
#else
    return exp2f(x);
#endif
}
__device__ __forceinline__ float frcp(float x) {
#if __has_builtin(__builtin_amdgcn_rcpf)
    return __builtin_amdgcn_rcpf(x);
#else
    return 1.f / x;
#endif
}
__device__ __forceinline__ float sigm(float x)  { return frcp(1.f + fexp2(-1.44269504f * x)); }
__device__ __forceinline__ float ftanh(float x) { return 1.f - 2.f * frcp(1.f + fexp2(2.88539008f * x)); }

__device__ __forceinline__ float fdot2f(half2v a, half2v b, float c) {
#if __has_builtin(__builtin_amdgcn_fdot2)
    return __builtin_amdgcn_fdot2(a, b, c, false);
#else
    return c + (float)a.x * (float)b.x + (float)a.y * (float)b.y;
#endif
}

__device__ __forceinline__ half2v pack2(float a, float b) {
    half2v r; r.x = (_Float16)a; r.y = (_Float16)b; return r;
}

// shared gate mapping (k_xw writer == lstm tail reader, indexed by tid):
// lane l<32: unit u, xw = (i_u, g_u) | lane l>=32: unit u, xw = (f_u, o_u)
// u = (tid>>6)*32 + (l&31)
__device__ __forceinline__ void gate_map(int tid, int& u, bool& lo, int& g0, int& g1) {
    int l = tid & 63;
    u = ((tid >> 6) << 5) + (l & 31);
    lo = (l < 32);
    g0 = lo ? u : 128 + u;
    g1 = lo ? 256 + u : 384 + u;
}

// ---------------------------------------------------------------------------
// K1: byte-decompose + embedding gather + encoder MLP (both pc and addr)
// ---------------------------------------------------------------------------
__global__ __launch_bounds__(256) void k_embed(
    const int* __restrict__ inp, const float* __restrict__ pc_emb,
    const float* __restrict__ ad_emb, const float* __restrict__ encW,
    const float* __restrict__ encB, float* __restrict__ emb)
{
    int idx = blockIdx.x * 256 + threadIdx.x;
    int b = idx >> 11, t = idx & 2047;
    size_t base = (size_t)b * SS + t;
    int2 pa = ((const int2*)inp)[base];
    float* outp = emb + base * INS;

    float in[128];
    #pragma unroll
    for (int st = 0; st < 2; st++) {
        int v = (st == 0) ? pa.x : pa.y;
        const float* tbl = (st == 0) ? pc_emb : ad_emb;
        #pragma unroll
        for (int i = 0; i < 4; i++) {
            int by = (v >> (24 - 8 * i)) & 255;
            const float4* row = (const float4*)(tbl + ((size_t)i * 256 + by) * EMBS);
            #pragma unroll
            for (int k = 0; k < 8; k++) {
                float4 f = row[k];
                in[i * 32 + k * 4 + 0] = f.x;
                in[i * 32 + k * 4 + 1] = f.y;
                in[i * 32 + k * 4 + 2] = f.z;
                in[i * 32 + k * 4 + 3] = f.w;
            }
        }
        for (int e = 0; e < EMBS; e++) {
            const float* w = encW + e * 128;
            float acc = encB[e];
            #pragma unroll
            for (int k = 0; k < 128; k++) acc += in[k] * w[k];
            outp[st * EMBS + e] = sigm(acc);
        }
    }
}

// ---------------------------------------------------------------------------
// K2: dist[b][j] = mean over t of emb[b][t][j]
// ---------------------------------------------------------------------------
__global__ __launch_bounds__(256) void k_dist(const float* __restrict__ emb,
                                              float* __restrict__ dist)
{
    int b = blockIdx.x;
    int j = threadIdx.x & 63;
    int grp = threadIdx.x >> 6;
    float s = 0.f;
    for (int t = grp; t < SS; t += 4) s += emb[((size_t)b * SS + t) * INS + j];
    __shared__ float red[4][64];
    red[grp][j] = s;
    __syncthreads();
    if (grp == 0)
        dist[b * 64 + j] = (red[0][j] + red[1][j] + red[2][j] + red[3][j]) * (1.f / SS);
}

// ---------------------------------------------------------------------------
// K_XW: xw[row][tid] = pack2(g0-row dot x + biases, g1-row dot x + biases)
// ---------------------------------------------------------------------------
#define XW_ROWS 64
__global__ __launch_bounds__(256) void k_xw(
    const float* __restrict__ emb, const float* __restrict__ Wih,
    const float* __restrict__ bih, const float* __restrict__ bhh,
    half2v* __restrict__ xwv)      // [row][256] half2v
{
    int tid = threadIdx.x;
    size_t r0 = (size_t)blockIdx.x * XW_ROWS;
    int u, g0, g1; bool lo;
    gate_map(tid, u, lo, g0, g1);

    half2v wa[32], wb[32];
    const float* pa_ = Wih + (size_t)g0 * INS;
    const float* pb_ = Wih + (size_t)g1 * INS;
    #pragma unroll
    for (int i = 0; i < 32; i++) {
        wa[i] = pack2(pa_[2 * i], pa_[2 * i + 1]);
        wb[i] = pack2(pb_[2 * i], pb_[2 * i + 1]);
    }
    float ba = bih[g0] + bhh[g0], bb = bih[g1] + bhh[g1];

    __shared__ alignas(16) half2v xsh[XW_ROWS * 32];   // 8 KiB
    const float4* src = (const float4*)(emb + r0 * INS);
    #pragma unroll
    for (int k = 0; k < 4; k++) {
        int fi = k * 256 + tid;
        float4 v = src[fi];
        xsh[fi * 2]     = pack2(v.x, v.y);
        xsh[fi * 2 + 1] = pack2(v.z, v.w);
    }
    __syncthreads();

    #pragma unroll 2
    for (int r = 0; r < XW_ROWS; r++) {
        const half2v* xr = &xsh[r * 32];
        float a0 = 0.f, a1 = 0.f, b0 = 0.f, b1 = 0.f;
        #pragma unroll
        for (int i = 0; i < 32; i += 2) {
            half2v x0 = xr[i], x1 = xr[i + 1];
            a0 = fdot2f(x0, wa[i], a0);
            a1 = fdot2f(x1, wa[i + 1], a1);
            b0 = fdot2f(x0, wb[i], b0);
            b1 = fdot2f(x1, wb[i + 1], b1);
        }
        xwv[(r0 + r) * 256 + tid] = pack2(ba + a0 + a1, bb + b0 + b1);
    }
}

// ---------------------------------------------------------------------------
// K3: LSTM via MFMA GEMV (B-broadcast). Wave w owns gate rows [128w,128w+128)
// (w: 0=i, 1=f, 2=g, 3=o) as 8 M-tiles x 4 K-MFMAs of 16x16x32_f16.
// h is replicated into all 16 B-columns (every lane reads the same h frag),
// so every C column is valid; lane (l&15)==m scatters tile m's f32x4 C-frag
// (4 gate rows) to LDS gates[512]. Tail = R6 structure (unchanged xw layout),
// 2 raw lgkm-only barriers/step; 4-deep rotation-free xw prefetch.
// ---------------------------------------------------------------------------
__global__ __launch_bounds__(256, 1) void k_lstm7(
    const half2v* __restrict__ xw, const float* __restrict__ h0,
    const float* __restrict__ c0, const float* __restrict__ Whh,
    float* __restrict__ hfin)
{
    int b = blockIdx.x;
    int tid = threadIdx.x;
    int w = tid >> 6;            // wave = gate type
    int l = tid & 63;
    int lrow = l & 15;           // A row within tile / C col
    int lgrp = l >> 4;           // k-group (8 f16 each) / C row-group

    int u, tg0, tg1; bool lo;
    gate_map(tid, u, lo, tg0, tg1);

    // A fragments: wave w, tile m, K-step kt: rows 128w+16m+lrow,
    // k = 32kt + 8*lgrp + j  (same per-lane k-indexing used for B -> any HW
    // k-permutation cancels). 8x4x4 = 128 VGPRs.
    half8 wA[8][4];
    #pragma unroll
    for (int m = 0; m < 8; m++) {
        #pragma unroll
        for (int kt = 0; kt < 4; kt++) {
            const float* src = Whh + (size_t)(w * 128 + m * 16 + lrow) * HS + kt * 32 + lgrp * 8;
            half8 v;
            #pragma unroll
            for (int j = 0; j < 8; j++) v[j] = (_Float16)src[j];
            wA[m][kt] = v;
        }
    }

    __shared__ alignas(16) _Float16 hsh[2][HS];   // double-buffered h (f16)
    __shared__ alignas(16) float gates[512];      // scattered pre-activations

    float c = 0.f, h = 0.f;
    if (!lo) c = c0[b * HS + u];                  // hi lanes own c state
    if (tid < 128) hsh[0][tid] = (_Float16)h0[b * HS + tid];
    __syncthreads();

    const half2v* xwrow = xw + (size_t)b * SS * 256 + tid;
    half2v xb0 = xwrow[0];
    half2v xb1 = xwrow[256];
    half2v xb2 = xwrow[512];
    half2v xb3 = xwrow[768];

    const f32x4 zero4 = {0.f, 0.f, 0.f, 0.f};

// one step. XB: xw(t) prefetch reg (reloaded for t+4 -> 4-step distance);
// RB: compile-time LDS h buffer index.
#define LSTEP(XB, RB, TN)                                                      \
    {                                                                          \
        /* B fragments: broadcast h to all 16 cols: lane reads k-slice only */ \
        const half8* hb = (const half8*)hsh[RB];                               \
        half8 bf0 = hb[lgrp];                                                  \
        half8 bf1 = hb[4 + lgrp];                                              \
        half8 bf2 = hb[8 + lgrp];                                              \
        half8 bf3 = hb[12 + lgrp];                                             \
        f32x4 acc[8];                                                          \
        _Pragma("unroll")                                                      \
        for (int m_ = 0; m_ < 8; m_++) {                                       \
            acc[m_] = __builtin_amdgcn_mfma_f32_16x16x32_f16(wA[m_][0], bf0, zero4, 0, 0, 0); \
            acc[m_] = __builtin_amdgcn_mfma_f32_16x16x32_f16(wA[m_][1], bf1, acc[m_], 0, 0, 0); \
            acc[m_] = __builtin_amdgcn_mfma_f32_16x16x32_f16(wA[m_][2], bf2, acc[m_], 0, 0, 0); \
            acc[m_] = __builtin_amdgcn_mfma_f32_16x16x32_f16(wA[m_][3], bf3, acc[m_], 0, 0, 0); \
        }                                                                      \
        /* scatter: col-m lanes write tile m's 4 rows (one b128 each) */       \
        _Pragma("unroll")                                                      \
        for (int m_ = 0; m_ < 8; m_++)                                         \
            if (lrow == m_)                                                    \
                *(f32x4*)&gates[w * 128 + m_ * 16 + lgrp * 4] = acc[m_];       \
        asm volatile("s_waitcnt lgkmcnt(0)" ::: "memory");                     \
        __builtin_amdgcn_s_barrier();                                          \
        __builtin_amdgcn_sched_barrier(0);                                     \
        /* tail (R6): lo thread: i,g | hi thread: f,o for unit u */            \
        float pre0 = gates[tg0] + (float)XB.x;                                 \
        float pre1 = gates[tg1] + (float)XB.y;                                 \
        float act0 = sigm(pre0);                    /* lo: i | hi: f */        \
        float act1 = lo ? ftanh(pre1) : sigm(pre1); /* lo: g | hi: o */        \
        float pig = __shfl_xor(act0 * act1, 32, 64); /* hi receives i*g */     \
        if (!lo) {                                                             \
            c = __builtin_fmaf(act0, c, pig);                                  \
            h = act1 * ftanh(c);                                               \
            hsh[RB ^ 1][u] = (_Float16)h;                                      \
        }                                                                      \
        {                                                                      \
            int tn_ = (TN) < SS ? (TN) : (SS - 1);                             \
            XB = xwrow[(size_t)tn_ * 256];                                     \
        }                                                                      \
        asm volatile("s_waitcnt lgkmcnt(0)" ::: "memory");                     \
        __builtin_amdgcn_s_barrier();                                          \
        __builtin_amdgcn_sched_barrier(0);                                     \
    }

    for (int t = 0; t < SS; t += 4) {
        LSTEP(xb0, 0, t + 4)
        LSTEP(xb1, 1, t + 5)
        LSTEP(xb2, 0, t + 6)
        LSTEP(xb3, 1, t + 7)
    }
#undef LSTEP

    if (!lo) hfin[b * HS + u] = h;
}

// ---------------------------------------------------------------------------
// K3 (fallback, ws too small for xW)
// ---------------------------------------------------------------------------
__global__ __launch_bounds__(256, 1) void k_lstm_fb(
    const float* __restrict__ emb, const float* __restrict__ h0,
    const float* __restrict__ c0, const float* __restrict__ Wih,
    const float* __restrict__ Whh, const float* __restrict__ bih,
    const float* __restrict__ bhh, float* __restrict__ hfin)
{
    int b = blockIdx.x;
    int tid = threadIdx.x;

    half2v wih[2][32], whh[2][64];
    #pragma unroll
    for (int g = 0; g < 2; g++) {
        int gg = tid + g * 256;
        const float* wr = Wih + (size_t)gg * INS;
        #pragma unroll
        for (int i = 0; i < 32; i++) wih[g][i] = pack2(wr[2 * i], wr[2 * i + 1]);
        const float* hr = Whh + (size_t)gg * HS;
        #pragma unroll
        for (int i = 0; i < 64; i++) whh[g][i] = pack2(hr[2 * i], hr[2 * i + 1]);
    }
    float bias0 = bih[tid] + bhh[tid];
    float bias1 = bih[tid + 256] + bhh[tid + 256];

    __shared__ alignas(16) half2v xh[96];
    __shared__ float f_act[128], o_act[128];
    __shared__ float xf[64], hf[128];

    float c = 0.f, h = 0.f;
    if (tid < 128) c = c0[b * HS + tid];

    const float* xrow = emb + (size_t)b * SS * INS;
    if (tid < 64) xf[tid] = xrow[tid];
    if (tid < 128) hf[tid] = h0[b * HS + tid];
    __syncthreads();
    if (tid < 32) xh[tid] = pack2(xf[2 * tid], xf[2 * tid + 1]);
    else if (tid < 96) { int uu = tid - 32; xh[tid] = pack2(hf[2 * uu], hf[2 * uu + 1]); }
    __syncthreads();

    for (int t = 0; t < SS; t++) {
        float xn = 0.f;
        if (tid >= 128 && tid < 192 && t + 1 < SS) xn = xrow[(size_t)(t + 1) * INS + (tid - 128)];

        float a0a = 0.f, a0b = 0.f, a1a = 0.f, a1b = 0.f;
        #pragma unroll
        for (int i = 0; i < 32; i += 2) {
            half2v x0 = xh[i], x1 = xh[i + 1];
            a0a = fdot2f(x0, wih[0][i], a0a);
            a0b = fdot2f(x1, wih[0][i + 1], a0b);
            a1a = fdot2f(x0, wih[1][i], a1a);
            a1b = fdot2f(x1, wih[1][i + 1], a1b);
        }
        #pragma unroll
        for (int i = 0; i < 64; i += 2) {
            half2v h0v = xh[32 + i], h1v = xh[32 + i + 1];
            a0a = fdot2f(h0v, whh[0][i], a0a);
            a0b = fdot2f(h1v, whh[0][i + 1], a0b);
            a1a = fdot2f(h0v, whh[1][i], a1a);
            a1b = fdot2f(h1v, whh[1][i + 1], a1b);
        }
        float a0 = bias0 + a0a + a0b;
        float a1 = bias1 + a1a + a1b;

        float iact = 0.f, gact = 0.f;
        if (tid < 128) { iact = sigm(a0); gact = ftanh(a1); }
        else           { f_act[tid - 128] = sigm(a0); o_act[tid - 128] = sigm(a1); }
        __syncthreads();

        if (tid < 128) {
            c = f_act[tid] * c + iact * gact;
            h = o_act[tid] * ftanh(c);
            hf[tid] = h;
        } else if (tid < 192) {
            xf[tid - 128] = xn;
        }
        __syncthreads();

        if (tid < 32) xh[tid] = pack2(xf[2 * tid], xf[2 * tid + 1]);
        else if (tid < 96) { int uu = tid - 32; xh[tid] = pack2(hf[2 * uu], hf[2 * uu + 1]); }
        __syncthreads();
    }
    if (tid < 128) hfin[b * HS + tid] = h;
}

// ---------------------------------------------------------------------------
// K4: decoder logits + T=1e-3 softmax + freq-rec head. one block per b.
// ---------------------------------------------------------------------------
__global__ __launch_bounds__(256) void k_head(
    const float* __restrict__ hfin, const float* __restrict__ decW,
    const float* __restrict__ decB, const float* __restrict__ ad_emb,
    const float* __restrict__ encW, const float* __restrict__ encB,
    const float* __restrict__ dist, const float* __restrict__ fc1W,
    const float* __restrict__ fc1b, const float* __restrict__ fc2W,
    const float* __restrict__ fc2b, float* __restrict__ outp)
{
    int b = blockIdx.x;
    int tid = threadIdx.x;
    __shared__ float hsh[128];
    __shared__ float logit_s[4][256];
    __shared__ float probs_s[4][256];
    __shared__ float be_s[128];
    __shared__ float fe_dist[96];
    __shared__ float fr1[10];

    if (tid < 128) hsh[tid] = hfin[b * HS + tid];
    __syncthreads();

    #pragma unroll
    for (int k = 0; k < 4; k++) {
        const float* w = decW + ((size_t)k * OUTS + tid) * HS;
        float acc = decB[k * OUTS + tid];
        #pragma unroll 8
        for (int hh = 0; hh < HS; hh++) acc += hsh[hh] * w[hh];
        logit_s[k][tid] = acc;
        outp[65536 + k * 16384 + b * 256 + tid] = acc;
    }
    __syncthreads();

    {
        int k = tid >> 6, lane = tid & 63;
        float v0 = logit_s[k][lane],       v1 = logit_s[k][lane + 64];
        float v2 = logit_s[k][lane + 128], v3 = logit_s[k][lane + 192];
        float m = fmaxf(fmaxf(v0, v1), fmaxf(v2, v3));
        for (int off = 32; off; off >>= 1) m = fmaxf(m, __shfl_xor(m, off, 64));
        float e0 = fexp2((v0 - m) * 1442.695041f), e1 = fexp2((v1 - m) * 1442.695041f);
        float e2 = fexp2((v2 - m) * 1442.695041f), e3 = fexp2((v3 - m) * 1442.695041f);
        float s = e0 + e1 + e2 + e3;
        for (int off = 32; off; off >>= 1) s += __shfl_xor(s, off, 64);
        float inv = 1.f / s;
        float p0 = e0 * inv, p1 = e1 * inv, p2 = e2 * inv, p3 = e3 * inv;
        probs_s[k][lane] = p0;        probs_s[k][lane + 64] = p1;
        probs_s[k][lane + 128] = p2;  probs_s[k][lane + 192] = p3;
        outp[k * 16384 + b * 256 + lane] = p0;
        outp[k * 16384 + b * 256 + lane + 64] = p1;
        outp[k * 16384 + b * 256 + lane + 128] = p2;
        outp[k * 16384 + b * 256 + lane + 192] = p3;
    }
    __syncthreads();

    if (tid < 128) {
        int k = tid >> 5, e = tid & 31;
        const float* te = ad_emb + (size_t)k * OUTS * EMBS + e;
        float acc = 0.f;
        #pragma unroll 8
        for (int o = 0; o < OUTS; o++) acc += probs_s[k][o] * te[o * EMBS];
        be_s[tid] = acc;
    }
    __syncthreads();

    if (tid < 32) {
        const float* w = encW + tid * 128;
        float acc = encB[tid];
        #pragma unroll 8
        for (int kk = 0; kk < 128; kk++) acc += be_s[kk] * w[kk];
        fe_dist[tid] = sigm(acc);
    } else if (tid < 96) {
        fe_dist[tid] = dist[b * 64 + (tid - 32)];
    }
    __syncthreads();

    if (tid < 10) {
        float acc = fc1b[tid];
        for (int kk = 0; kk < 96; kk++) acc += fe_dist[kk] * fc1W[tid * 96 + kk];
        fr1[tid] = fmaxf(acc, 0.f);
    }
    __syncthreads();

    if (tid < 2) {
        float acc = fc2b[tid];
        for (int kk = 0; kk < 10; kk++) acc += fr1[kk] * fc2W[tid * 10 + kk];
        outp[131072 + tid * 64 + b] = sigm(acc);
    }
}

// ---------------------------------------------------------------------------
extern "C" void kernel_launch(void* const* d_in, const int* in_sizes, int n_in,
                              void* d_out, int out_size, void* d_ws, size_t ws_size,
                              hipStream_t stream)
{
    const int*   inp    = (const int*)d_in[0];
    const float* h0     = (const float*)d_in[1];
    const float* c0     = (const float*)d_in[2];
    const float* pc_emb = (const float*)d_in[3];
    const float* ad_emb = (const float*)d_in[4];
    const float* encW   = (const float*)d_in[5];
    const float* encB   = (const float*)d_in[6];
    const float* Wih    = (const float*)d_in[7];
    const float* Whh    = (const float*)d_in[8];
    const float* bih    = (const float*)d_in[9];
    const float* bhh    = (const float*)d_in[10];
    const float* decW   = (const float*)d_in[11];
    const float* decB   = (const float*)d_in[12];
    const float* fc1W   = (const float*)d_in[13];
    const float* fc1b   = (const float*)d_in[14];
    const float* fc2W   = (const float*)d_in[15];
    const float* fc2b   = (const float*)d_in[16];

    if (ws_size < WS_SMALL * 4ull) return;

    float* ws   = (float*)d_ws;
    float* emb  = ws;
    float* dist = ws + WS_DIST;
    float* hfin = ws + WS_HFIN;
    float* outp = (float*)d_out;
    bool big = (ws_size >= WS_BIG * 4ull);

    hipLaunchKernelGGL(k_embed, dim3(512), dim3(256), 0, stream,
                       inp, pc_emb, ad_emb, encW, encB, emb);
    hipLaunchKernelGGL(k_dist, dim3(64), dim3(256), 0, stream, emb, dist);
    if (big) {
        half2v* xwv = (half2v*)(ws + WS_XW);
        hipLaunchKernelGGL(k_xw, dim3(BS * SS / XW_ROWS), dim3(256), 0, stream,
                           emb, Wih, bih, bhh, xwv);
        hipLaunchKernelGGL(k_lstm7, dim3(64), dim3(256), 0, stream,
                           xwv, h0, c0, Whh, hfin);
    } else {
        hipLaunchKernelGGL(k_lstm_fb, dim3(64), dim3(256), 0, stream,
                           emb, h0, c0, Wih, Whh, bih, bhh, hfin);
    }
    hipLaunchKernelGGL(k_head, dim3(64), dim3(256), 0, stream,
                       hfin, decW, decB, ad_emb, encW, encB, dist,
                       fc1W, fc1b, fc2W, fc2b, outp);
}

// Round 8
// 1423.983 us; speedup vs baseline: 1.2791x; 1.2791x over previous
//
#include <hip/hip_runtime.h>
#include <math.h>
#include <stdint.h>

#define EMBS 32
#define INS 64
#define HS 128
#define OUTS 256
#define BS 64
#define SS 2048

typedef _Float16 half2v __attribute__((ext_vector_type(2)));
typedef _Float16 half8  __attribute__((ext_vector_type(8)));
typedef float f32x4 __attribute__((ext_vector_type(4)));

typedef union { half8 v; half2v p[4]; } h8u;

// ws layout (4B elems):
// emb [B][S][IN] f32 | dist [B][IN] f32 | hfin [B][H] f32 | P [2][4][256][32] f32 | xw [B][S][256] half2v
static constexpr size_t WS_DIST  = (size_t)BS * SS * INS;
static constexpr size_t WS_HFIN  = WS_DIST + (size_t)BS * INS;
static constexpr size_t WS_P     = WS_HFIN + (size_t)BS * HS;
static constexpr size_t WS_XW    = WS_P + 2ull * 4 * 256 * 32;
static constexpr size_t WS_SMALL = WS_XW;
static constexpr size_t WS_BIG   = WS_XW + (size_t)BS * SS * 256;

__device__ __forceinline__ float fexp2(float x) {
#if __has_builtin(__builtin_amdgcn_exp2f)
    return __builtin_amdgcn_exp2f(x);
#else
    return exp2f(x);
#endif
}
__device__ __forceinline__ float frcp(float x) {
#if __has_builtin(__builtin_amdgcn_rcpf)
    return __builtin_amdgcn_rcpf(x);
#else
    return 1.f / x;
#endif
}
__device__ __forceinline__ float sigm(float x)  { return frcp(1.f + fexp2(-1.44269504f * x)); }
__device__ __forceinline__ float ftanh(float x) { return 1.f - 2.f * frcp(1.f + fexp2(2.88539008f * x)); }

__device__ __forceinline__ float fdot2f(half2v a, half2v b, float c) {
#if __has_builtin(__builtin_amdgcn_fdot2)
    return __builtin_amdgcn_fdot2(a, b, c, false);
#else
    return c + (float)a.x * (float)b.x + (float)a.y * (float)b.y;
#endif
}

__device__ __forceinline__ half2v pack2(float a, float b) {
    half2v r; r.x = (_Float16)a; r.y = (_Float16)b; return r;
}

// shared gate mapping (k_xw writer == lstm tail reader, indexed by tid):
// lane l<32: unit u, xw = (i_u, g_u) | lane l>=32: unit u, xw = (f_u, o_u)
__device__ __forceinline__ void gate_map(int tid, int& u, bool& lo, int& g0, int& g1) {
    int l = tid & 63;
    u = ((tid >> 6) << 5) + (l & 31);
    lo = (l < 32);
    g0 = lo ? u : 128 + u;
    g1 = lo ? 256 + u : 384 + u;
}

// ---------------------------------------------------------------------------
// K_PRE: P[st][i][byte][e] = encW[e, 32i:32i+32] . tbl_st_i[byte]  (+encB at i==0)
// 65536 outputs, 32 MAC each.
// ---------------------------------------------------------------------------
__global__ __launch_bounds__(256) void k_pre(
    const float* __restrict__ pc_emb, const float* __restrict__ ad_emb,
    const float* __restrict__ encW, const float* __restrict__ encB,
    float* __restrict__ P)
{
    int idx = blockIdx.x * 256 + threadIdx.x;       // 256 blocks
    int e = idx & 31, by = (idx >> 5) & 255, i = (idx >> 13) & 3, st = idx >> 15;
    const float* tbl = (st ? ad_emb : pc_emb) + ((size_t)i * 256 + by) * EMBS;
    const float* w = encW + e * 128 + i * 32;
    float acc = (i == 0) ? encB[e] : 0.f;
    #pragma unroll
    for (int k = 0; k < 32; k++) acc += w[k] * tbl[k];
    P[idx] = acc;
}

// ---------------------------------------------------------------------------
// K1: embed via P-gather: emb = sigm(sum_i P[st][i][byte_i])
// ---------------------------------------------------------------------------
__global__ __launch_bounds__(256) void k_embed2(
    const int* __restrict__ inp, const float* __restrict__ P,
    float* __restrict__ emb)
{
    int idx = blockIdx.x * 256 + threadIdx.x;       // 512 blocks = B*S
    size_t base = (size_t)idx;
    int2 pa = ((const int2*)inp)[base];
    float* outp = emb + base * INS;

    #pragma unroll
    for (int st = 0; st < 2; st++) {
        int v = st ? pa.y : pa.x;
        const float* Ps = P + st * 32768;
        float acc[32];
        #pragma unroll
        for (int i = 0; i < 4; i++) {
            int by = (v >> (24 - 8 * i)) & 255;
            const float4* row = (const float4*)(Ps + ((size_t)i * 256 + by) * 32);
            #pragma unroll
            for (int k = 0; k < 8; k++) {
                float4 f = row[k];
                if (i == 0) {
                    acc[k * 4 + 0] = f.x; acc[k * 4 + 1] = f.y;
                    acc[k * 4 + 2] = f.z; acc[k * 4 + 3] = f.w;
                } else {
                    acc[k * 4 + 0] += f.x; acc[k * 4 + 1] += f.y;
                    acc[k * 4 + 2] += f.z; acc[k * 4 + 3] += f.w;
                }
            }
        }
        #pragma unroll
        for (int e = 0; e < 32; e++) outp[st * 32 + e] = sigm(acc[e]);
    }
}

// ---------------------------------------------------------------------------
// K2: dist[b][j] = mean over t of emb[b][t][j]
// ---------------------------------------------------------------------------
__global__ __launch_bounds__(256) void k_dist(const float* __restrict__ emb,
                                              float* __restrict__ dist)
{
    int b = blockIdx.x;
    int j = threadIdx.x & 63;
    int grp = threadIdx.x >> 6;
    float s = 0.f;
    for (int t = grp; t < SS; t += 4) s += emb[((size_t)b * SS + t) * INS + j];
    __shared__ float red[4][64];
    red[grp][j] = s;
    __syncthreads();
    if (grp == 0)
        dist[b * 64 + j] = (red[0][j] + red[1][j] + red[2][j] + red[3][j]) * (1.f / SS);
}

// ---------------------------------------------------------------------------
// K_XW: xw[row][tid] = pack2(g0-row dot x + biases, g1-row dot x + biases)
// LDS x reads vectorized to ds_read_b128.
// ---------------------------------------------------------------------------
#define XW_ROWS 64
__global__ __launch_bounds__(256) void k_xw(
    const float* __restrict__ emb, const float* __restrict__ Wih,
    const float* __restrict__ bih, const float* __restrict__ bhh,
    half2v* __restrict__ xwv)      // [row][256] half2v
{
    int tid = threadIdx.x;
    size_t r0 = (size_t)blockIdx.x * XW_ROWS;
    int u, g0, g1; bool lo;
    gate_map(tid, u, lo, g0, g1);

    half2v wa[32], wb[32];
    const float* pa_ = Wih + (size_t)g0 * INS;
    const float* pb_ = Wih + (size_t)g1 * INS;
    #pragma unroll
    for (int i = 0; i < 32; i++) {
        wa[i] = pack2(pa_[2 * i], pa_[2 * i + 1]);
        wb[i] = pack2(pb_[2 * i], pb_[2 * i + 1]);
    }
    float ba = bih[g0] + bhh[g0], bb = bih[g1] + bhh[g1];

    __shared__ alignas(16) half2v xsh[XW_ROWS * 32];   // 8 KiB
    const float4* src = (const float4*)(emb + r0 * INS);
    #pragma unroll
    for (int k = 0; k < 4; k++) {
        int fi = k * 256 + tid;
        float4 v = src[fi];
        xsh[fi * 2]     = pack2(v.x, v.y);
        xsh[fi * 2 + 1] = pack2(v.z, v.w);
    }
    __syncthreads();

    #pragma unroll 2
    for (int r = 0; r < XW_ROWS; r++) {
        const half8* xr8 = (const half8*)&xsh[r * 32];
        h8u x8[8];
        #pragma unroll
        for (int k = 0; k < 8; k++) x8[k].v = xr8[k];   // 8 x ds_read_b128
        float a0 = 0.f, a1 = 0.f, b0 = 0.f, b1 = 0.f;
        #pragma unroll
        for (int i = 0; i < 32; i += 2) {
            half2v x0 = x8[i >> 2].p[i & 3], x1 = x8[(i + 1) >> 2].p[(i + 1) & 3];
            a0 = fdot2f(x0, wa[i], a0);
            a1 = fdot2f(x1, wa[i + 1], a1);
            b0 = fdot2f(x0, wb[i], b0);
            b1 = fdot2f(x1, wb[i + 1], b1);
        }
        xwv[(r0 + r) * 256 + tid] = pack2(ba + a0 + a1, bb + b0 + b1);
    }
}

// ---------------------------------------------------------------------------
// K3: LSTM (R6 structure, proven): K-split-2 per lane pair, shfl_xor(32)
// exchanges, 4-deep rotation-free xw prefetch, 1 raw lgkm-only barrier/step.
// New vs R6: h read via 8 x ds_read_b128 (was 32 x b32), 8 accum chains.
// ---------------------------------------------------------------------------
__global__ __launch_bounds__(256, 1) void k_lstm8(
    const half2v* __restrict__ xw, const float* __restrict__ h0,
    const float* __restrict__ c0, const float* __restrict__ Whh,
    float* __restrict__ hfin)
{
    int b = blockIdx.x;
    int tid = threadIdx.x;
    int u, g0_, g1_; bool lo;
    gate_map(tid, u, lo, g0_, g1_);
    int koff = lo ? 0 : 64;        // my K-half (f16 elements)

    // all 4 gate rows of unit u, my K-half: 4 x 32 half2v = 128 VGPRs
    half2v wI[32], wF[32], wG[32], wO[32];
    {
        const float* rI = Whh + (size_t)(u)       * HS + koff;
        const float* rF = Whh + (size_t)(128 + u) * HS + koff;
        const float* rG = Whh + (size_t)(256 + u) * HS + koff;
        const float* rO = Whh + (size_t)(384 + u) * HS + koff;
        #pragma unroll
        for (int i = 0; i < 32; i++) {
            wI[i] = pack2(rI[2 * i], rI[2 * i + 1]);
            wF[i] = pack2(rF[2 * i], rF[2 * i + 1]);
            wG[i] = pack2(rG[2 * i], rG[2 * i + 1]);
            wO[i] = pack2(rO[2 * i], rO[2 * i + 1]);
        }
    }

    __shared__ alignas(16) _Float16 hsh[2][HS];
    float c = 0.f, h = 0.f;
    if (!lo) c = c0[b * HS + u];               // hi lanes own the c state
    if (tid < 128) hsh[0][tid] = (_Float16)h0[b * HS + tid];
    __syncthreads();

    const half2v* xwrow = xw + (size_t)b * SS * 256 + tid;
    half2v xb0 = xwrow[0];
    half2v xb1 = xwrow[256];
    half2v xb2 = xwrow[512];
    half2v xb3 = xwrow[768];

// one LSTM step. XB: xw(t) prefetch reg (reloaded for t+4 -> 4-step distance);
// RB: compile-time LDS h buffer index.
#define LSTEP(XB, RB, TN)                                                      \
    {                                                                          \
        const half8* hb8 = (const half8*)(&hsh[RB][0] + koff);                 \
        h8u h8[8];                                                             \
        _Pragma("unroll")                                                      \
        for (int k_ = 0; k_ < 8; k_++) h8[k_].v = hb8[k_];  /* 8x b128 */      \
        float pIa = 0.f, pFa = 0.f, pGa = 0.f, pOa = 0.f;                      \
        float pIb = 0.f, pFb = 0.f, pGb = 0.f, pOb = 0.f;                      \
        _Pragma("unroll")                                                      \
        for (int j_ = 0; j_ < 16; j_++) {                                      \
            half2v hv = h8[j_ >> 2].p[j_ & 3];                                 \
            pIa = fdot2f(hv, wI[j_], pIa);                                     \
            pFa = fdot2f(hv, wF[j_], pFa);                                     \
            pGa = fdot2f(hv, wG[j_], pGa);                                     \
            pOa = fdot2f(hv, wO[j_], pOa);                                     \
        }                                                                      \
        _Pragma("unroll")                                                      \
        for (int j_ = 16; j_ < 32; j_++) {                                     \
            half2v hv = h8[j_ >> 2].p[j_ & 3];                                 \
            pIb = fdot2f(hv, wI[j_], pIb);                                     \
            pFb = fdot2f(hv, wF[j_], pFb);                                     \
            pGb = fdot2f(hv, wG[j_], pGb);                                     \
            pOb = fdot2f(hv, wO[j_], pOb);                                     \
        }                                                                      \
        float pI = pIa + pIb, pF = pFa + pFb;                                  \
        float pG = pGa + pGb, pO = pOa + pOb;                                  \
        float r1 = __shfl_xor(lo ? pF : pI, 32, 64);                           \
        float r2 = __shfl_xor(lo ? pO : pG, 32, 64);                           \
        float pre0 = (lo ? pI : pF) + r1 + (float)XB.x;                        \
        float pre1 = (lo ? pG : pO) + r2 + (float)XB.y;                        \
        float act0 = sigm(pre0);                    /* lo: i | hi: f */        \
        float act1 = lo ? ftanh(pre1) : sigm(pre1); /* lo: g | hi: o */        \
        float pig = __shfl_xor(act0 * act1, 32, 64); /* hi receives i*g */     \
        if (!lo) {                                                             \
            c = __builtin_fmaf(act0, c, pig);                                  \
            h = act1 * ftanh(c);                                               \
            hsh[RB ^ 1][u] = (_Float16)h;                                      \
        }                                                                      \
        {                                                                      \
            int tn_ = (TN) < SS ? (TN) : (SS - 1);                             \
            XB = xwrow[(size_t)tn_ * 256];                                     \
        }                                                                      \
        asm volatile("s_waitcnt lgkmcnt(0)" ::: "memory");                     \
        __builtin_amdgcn_s_barrier();                                          \
        __builtin_amdgcn_sched_barrier(0);                                     \
    }

    for (int t = 0; t < SS; t += 4) {
        LSTEP(xb0, 0, t + 4)
        LSTEP(xb1, 1, t + 5)
        LSTEP(xb2, 0, t + 6)
        LSTEP(xb3, 1, t + 7)
    }
#undef LSTEP

    if (!lo) hfin[b * HS + u] = h;
}

// ---------------------------------------------------------------------------
// K3 (fallback, ws too small for xW)
// ---------------------------------------------------------------------------
__global__ __launch_bounds__(256, 1) void k_lstm_fb(
    const float* __restrict__ emb, const float* __restrict__ h0,
    const float* __restrict__ c0, const float* __restrict__ Wih,
    const float* __restrict__ Whh, const float* __restrict__ bih,
    const float* __restrict__ bhh, float* __restrict__ hfin)
{
    int b = blockIdx.x;
    int tid = threadIdx.x;

    half2v wih[2][32], whh[2][64];
    #pragma unroll
    for (int g = 0; g < 2; g++) {
        int gg = tid + g * 256;
        const float* wr = Wih + (size_t)gg * INS;
        #pragma unroll
        for (int i = 0; i < 32; i++) wih[g][i] = pack2(wr[2 * i], wr[2 * i + 1]);
        const float* hr = Whh + (size_t)gg * HS;
        #pragma unroll
        for (int i = 0; i < 64; i++) whh[g][i] = pack2(hr[2 * i], hr[2 * i + 1]);
    }
    float bias0 = bih[tid] + bhh[tid];
    float bias1 = bih[tid + 256] + bhh[tid + 256];

    __shared__ alignas(16) half2v xh[96];
    __shared__ float f_act[128], o_act[128];
    __shared__ float xf[64], hf[128];

    float c = 0.f, h = 0.f;
    if (tid < 128) c = c0[b * HS + tid];

    const float* xrow = emb + (size_t)b * SS * INS;
    if (tid < 64) xf[tid] = xrow[tid];
    if (tid < 128) hf[tid] = h0[b * HS + tid];
    __syncthreads();
    if (tid < 32) xh[tid] = pack2(xf[2 * tid], xf[2 * tid + 1]);
    else if (tid < 96) { int uu = tid - 32; xh[tid] = pack2(hf[2 * uu], hf[2 * uu + 1]); }
    __syncthreads();

    for (int t = 0; t < SS; t++) {
        float xn = 0.f;
        if (tid >= 128 && tid < 192 && t + 1 < SS) xn = xrow[(size_t)(t + 1) * INS + (tid - 128)];

        float a0a = 0.f, a0b = 0.f, a1a = 0.f, a1b = 0.f;
        #pragma unroll
        for (int i = 0; i < 32; i += 2) {
            half2v x0 = xh[i], x1 = xh[i + 1];
            a0a = fdot2f(x0, wih[0][i], a0a);
            a0b = fdot2f(x1, wih[0][i + 1], a0b);
            a1a = fdot2f(x0, wih[1][i], a1a);
            a1b = fdot2f(x1, wih[1][i + 1], a1b);
        }
        #pragma unroll
        for (int i = 0; i < 64; i += 2) {
            half2v h0v = xh[32 + i], h1v = xh[32 + i + 1];
            a0a = fdot2f(h0v, whh[0][i], a0a);
            a0b = fdot2f(h1v, whh[0][i + 1], a0b);
            a1a = fdot2f(h0v, whh[1][i], a1a);
            a1b = fdot2f(h1v, whh[1][i + 1], a1b);
        }
        float a0 = bias0 + a0a + a0b;
        float a1 = bias1 + a1a + a1b;

        float iact = 0.f, gact = 0.f;
        if (tid < 128) { iact = sigm(a0); gact = ftanh(a1); }
        else           { f_act[tid - 128] = sigm(a0); o_act[tid - 128] = sigm(a1); }
        __syncthreads();

        if (tid < 128) {
            c = f_act[tid] * c + iact * gact;
            h = o_act[tid] * ftanh(c);
            hf[tid] = h;
        } else if (tid < 192) {
            xf[tid - 128] = xn;
        }
        __syncthreads();

        if (tid < 32) xh[tid] = pack2(xf[2 * tid], xf[2 * tid + 1]);
        else if (tid < 96) { int uu = tid - 32; xh[tid] = pack2(hf[2 * uu], hf[2 * uu + 1]); }
        __syncthreads();
    }
    if (tid < 128) hfin[b * HS + tid] = h;
}

// ---------------------------------------------------------------------------
// K4: decoder logits + T=1e-3 softmax + freq-rec head. one block per b.
// Logit phase vectorized (f32x4 LDS reads, float4 weight loads).
// ---------------------------------------------------------------------------
__global__ __launch_bounds__(256) void k_head(
    const float* __restrict__ hfin, const float* __restrict__ decW,
    const float* __restrict__ decB, const float* __restrict__ ad_emb,
    const float* __restrict__ encW, const float* __restrict__ encB,
    const float* __restrict__ dist, const float* __restrict__ fc1W,
    const float* __restrict__ fc1b, const float* __restrict__ fc2W,
    const float* __restrict__ fc2b, float* __restrict__ outp)
{
    int b = blockIdx.x;
    int tid = threadIdx.x;
    __shared__ alignas(16) float hsh[128];
    __shared__ float logit_s[4][256];
    __shared__ float probs_s[4][256];
    __shared__ float be_s[128];
    __shared__ float fe_dist[96];
    __shared__ float fr1[10];

    if (tid < 128) hsh[tid] = hfin[b * HS + tid];
    __syncthreads();

    {
        f32x4 hv[32];
        const f32x4* h4 = (const f32x4*)hsh;
        #pragma unroll
        for (int j = 0; j < 32; j++) hv[j] = h4[j];
        #pragma unroll
        for (int k = 0; k < 4; k++) {
            const float4* w4 = (const float4*)(decW + ((size_t)k * OUTS + tid) * HS);
            float a0 = decB[k * OUTS + tid], a1 = 0.f;
            #pragma unroll
            for (int j = 0; j < 32; j++) {
                float4 wv = w4[j];
                a0 = __builtin_fmaf(hv[j][0], wv.x, a0);
                a1 = __builtin_fmaf(hv[j][1], wv.y, a1);
                a0 = __builtin_fmaf(hv[j][2], wv.z, a0);
                a1 = __builtin_fmaf(hv[j][3], wv.w, a1);
            }
            float acc = a0 + a1;
            logit_s[k][tid] = acc;
            outp[65536 + k * 16384 + b * 256 + tid] = acc;
        }
    }
    __syncthreads();

    {
        int k = tid >> 6, lane = tid & 63;
        float v0 = logit_s[k][lane],       v1 = logit_s[k][lane + 64];
        float v2 = logit_s[k][lane + 128], v3 = logit_s[k][lane + 192];
        float m = fmaxf(fmaxf(v0, v1), fmaxf(v2, v3));
        for (int off = 32; off; off >>= 1) m = fmaxf(m, __shfl_xor(m, off, 64));
        float e0 = fexp2((v0 - m) * 1442.695041f), e1 = fexp2((v1 - m) * 1442.695041f);
        float e2 = fexp2((v2 - m) * 1442.695041f), e3 = fexp2((v3 - m) * 1442.695041f);
        float s = e0 + e1 + e2 + e3;
        for (int off = 32; off; off >>= 1) s += __shfl_xor(s, off, 64);
        float inv = 1.f / s;
        float p0 = e0 * inv, p1 = e1 * inv, p2 = e2 * inv, p3 = e3 * inv;
        probs_s[k][lane] = p0;        probs_s[k][lane + 64] = p1;
        probs_s[k][lane + 128] = p2;  probs_s[k][lane + 192] = p3;
        outp[k * 16384 + b * 256 + lane] = p0;
        outp[k * 16384 + b * 256 + lane + 64] = p1;
        outp[k * 16384 + b * 256 + lane + 128] = p2;
        outp[k * 16384 + b * 256 + lane + 192] = p3;
    }
    __syncthreads();

    if (tid < 128) {
        int k = tid >> 5, e = tid & 31;
        const float* te = ad_emb + (size_t)k * OUTS * EMBS + e;
        float acc = 0.f;
        #pragma unroll 8
        for (int o = 0; o < OUTS; o++) acc += probs_s[k][o] * te[o * EMBS];
        be_s[tid] = acc;
    }
    __syncthreads();

    if (tid < 32) {
        const float* w = encW + tid * 128;
        float acc = encB[tid];
        #pragma unroll 8
        for (int kk = 0; kk < 128; kk++) acc += be_s[kk] * w[kk];
        fe_dist[tid] = sigm(acc);
    } else if (tid < 96) {
        fe_dist[tid] = dist[b * 64 + (tid - 32)];
    }
    __syncthreads();

    if (tid < 10) {
        float acc = fc1b[tid];
        for (int kk = 0; kk < 96; kk++) acc += fe_dist[kk] * fc1W[tid * 96 + kk];
        fr1[tid] = fmaxf(acc, 0.f);
    }
    __syncthreads();

    if (tid < 2) {
        float acc = fc2b[tid];
        for (int kk = 0; kk < 10; kk++) acc += fr1[kk] * fc2W[tid * 10 + kk];
        outp[131072 + tid * 64 + b] = sigm(acc);
    }
}

// ---------------------------------------------------------------------------
extern "C" void kernel_launch(void* const* d_in, const int* in_sizes, int n_in,
                              void* d_out, int out_size, void* d_ws, size_t ws_size,
                              hipStream_t stream)
{
    const int*   inp    = (const int*)d_in[0];
    const float* h0     = (const float*)d_in[1];
    const float* c0     = (const float*)d_in[2];
    const float* pc_emb = (const float*)d_in[3];
    const float* ad_emb = (const float*)d_in[4];
    const float* encW   = (const float*)d_in[5];
    const float* encB   = (const float*)d_in[6];
    const float* Wih    = (const float*)d_in[7];
    const float* Whh    = (const float*)d_in[8];
    const float* bih    = (const float*)d_in[9];
    const float* bhh    = (const float*)d_in[10];
    const float* decW   = (const float*)d_in[11];
    const float* decB   = (const float*)d_in[12];
    const float* fc1W   = (const float*)d_in[13];
    const float* fc1b   = (const float*)d_in[14];
    const float* fc2W   = (const float*)d_in[15];
    const float* fc2b   = (const float*)d_in[16];

    if (ws_size < WS_SMALL * 4ull) return;

    float* ws   = (float*)d_ws;
    float* emb  = ws;
    float* dist = ws + WS_DIST;
    float* hfin = ws + WS_HFIN;
    float* P    = ws + WS_P;
    float* outp = (float*)d_out;
    bool big = (ws_size >= WS_BIG * 4ull);

    hipLaunchKernelGGL(k_pre, dim3(256), dim3(256), 0, stream,
                       pc_emb, ad_emb, encW, encB, P);
    hipLaunchKernelGGL(k_embed2, dim3(512), dim3(256), 0, stream,
                       inp, P, emb);
    hipLaunchKernelGGL(k_dist, dim3(64), dim3(256), 0, stream, emb, dist);
    if (big) {
        half2v* xwv = (half2v*)(ws + WS_XW);
        hipLaunchKernelGGL(k_xw, dim3(BS * SS / XW_ROWS), dim3(256), 0, stream,
                           emb, Wih, bih, bhh, xwv);
        hipLaunchKernelGGL(k_lstm8, dim3(64), dim3(256), 0, stream,
                           xwv, h0, c0, Whh, hfin);
    } else {
        hipLaunchKernelGGL(k_lstm_fb, dim3(64), dim3(256), 0, stream,
                           emb, h0, c0, Wih, Whh, bih, bhh, hfin);
    }
    hipLaunchKernelGGL(k_head, dim3(64), dim3(256), 0, stream,
                       hfin, decW, decB, ad_emb, encW, encB, dist,
                       fc1W, fc1b, fc2W, fc2b, outp);
}

// Round 9
// 1271.982 us; speedup vs baseline: 1.4319x; 1.1195x over previous
//
#include <hip/hip_runtime.h>
#include <math.h>
#include <stdint.h>

#define EMBS 32
#define INS 64
#define HS 128
#define OUTS 256
#define BS 64
#define SS 2048

typedef _Float16 half2v __attribute__((ext_vector_type(2)));
typedef _Float16 half8  __attribute__((ext_vector_type(8)));
typedef float f32x4 __attribute__((ext_vector_type(4)));
typedef unsigned int uint2v __attribute__((ext_vector_type(2)));

typedef union { half8 v; half2v p[4]; } h8u;

// ws layout (4B elems):
// emb [B][S][IN] f32 | dist [B][IN] f32 | hfin [B][H] f32 | P [2][4][256][32] f32 | xw [B][S][256] half2v
static constexpr size_t WS_DIST  = (size_t)BS * SS * INS;
static constexpr size_t WS_HFIN  = WS_DIST + (size_t)BS * INS;
static constexpr size_t WS_P     = WS_HFIN + (size_t)BS * HS;
static constexpr size_t WS_XW    = WS_P + 2ull * 4 * 256 * 32;
static constexpr size_t WS_SMALL = WS_XW;
static constexpr size_t WS_BIG   = WS_XW + (size_t)BS * SS * 256;

__device__ __forceinline__ float fexp2(float x) {
#if __has_builtin(__builtin_amdgcn_exp2f)
    return __builtin_amdgcn_exp2f(x);
#else
    return exp2f(x);
#endif
}
__device__ __forceinline__ float frcp(float x) {
#if __has_builtin(__builtin_amdgcn_rcpf)
    return __builtin_amdgcn_rcpf(x);
#else
    return 1.f / x;
#endif
}
__device__ __forceinline__ float sigm(float x)  { return frcp(1.f + fexp2(-1.44269504f * x)); }
__device__ __forceinline__ float ftanh(float x) { return 1.f - 2.f * frcp(1.f + fexp2(2.88539008f * x)); }

__device__ __forceinline__ float fdot2f(half2v a, half2v b, float c) {
#if __has_builtin(__builtin_amdgcn_fdot2)
    return __builtin_amdgcn_fdot2(a, b, c, false);
#else
    return c + (float)a.x * (float)b.x + (float)a.y * (float)b.y;
#endif
}

__device__ __forceinline__ half2v pack2(float a, float b) {
    half2v r; r.x = (_Float16)a; r.y = (_Float16)b; return r;
}

// Exchange with lane^32 partner, VALU-only (v_permlane32_swap_b32).
// Semantics: vdst[32:63] <-> vsrc[0:31]. With both inputs = x:
//   r.x = {x_lo, x_lo}  (lane 32+j gets x[j])
//   r.y = {x_hi, x_hi}  (lane j    gets x[32+j])
// => partner value = lo ? r.y : r.x.   (R5 had this selection FLIPPED ->
// each lane read its own value; R6 passing with shfl proves the rest of the
// structure, so the flipped selection is the corrected primitive.)
__device__ __forceinline__ float pswap32(float x, bool lo) {
#if __has_builtin(__builtin_amdgcn_permlane32_swap)
    uint2v r = __builtin_amdgcn_permlane32_swap(
        __builtin_bit_cast(unsigned, x), __builtin_bit_cast(unsigned, x),
        false, false);
    return __builtin_bit_cast(float, lo ? r.y : r.x);
#else
    return __shfl_xor(x, 32, 64);   // safe fallback
#endif
}

// shared gate mapping (k_xw writer == lstm tail reader, indexed by tid):
// lane l<32: unit u, xw = (i_u, g_u) | lane l>=32: unit u, xw = (f_u, o_u)
__device__ __forceinline__ void gate_map(int tid, int& u, bool& lo, int& g0, int& g1) {
    int l = tid & 63;
    u = ((tid >> 6) << 5) + (l & 31);
    lo = (l < 32);
    g0 = lo ? u : 128 + u;
    g1 = lo ? 256 + u : 384 + u;
}

// ---------------------------------------------------------------------------
// K_PRE: P[st][i][byte][e] = encW[e, 32i:32i+32] . tbl_st_i[byte]  (+encB at i==0)
// ---------------------------------------------------------------------------
__global__ __launch_bounds__(256) void k_pre(
    const float* __restrict__ pc_emb, const float* __restrict__ ad_emb,
    const float* __restrict__ encW, const float* __restrict__ encB,
    float* __restrict__ P)
{
    int idx = blockIdx.x * 256 + threadIdx.x;       // 256 blocks
    int e = idx & 31, by = (idx >> 5) & 255, i = (idx >> 13) & 3, st = idx >> 15;
    const float* tbl = (st ? ad_emb : pc_emb) + ((size_t)i * 256 + by) * EMBS;
    const float* w = encW + e * 128 + i * 32;
    float acc = (i == 0) ? encB[e] : 0.f;
    #pragma unroll
    for (int k = 0; k < 32; k++) acc += w[k] * tbl[k];
    P[idx] = acc;
}

// ---------------------------------------------------------------------------
// K1: embed via P-gather: emb = sigm(sum_i P[st][i][byte_i])
// ---------------------------------------------------------------------------
__global__ __launch_bounds__(256) void k_embed2(
    const int* __restrict__ inp, const float* __restrict__ P,
    float* __restrict__ emb)
{
    int idx = blockIdx.x * 256 + threadIdx.x;       // 512 blocks = B*S
    size_t base = (size_t)idx;
    int2 pa = ((const int2*)inp)[base];
    float* outp = emb + base * INS;

    #pragma unroll
    for (int st = 0; st < 2; st++) {
        int v = st ? pa.y : pa.x;
        const float* Ps = P + st * 32768;
        float acc[32];
        #pragma unroll
        for (int i = 0; i < 4; i++) {
            int by = (v >> (24 - 8 * i)) & 255;
            const float4* row = (const float4*)(Ps + ((size_t)i * 256 + by) * 32);
            #pragma unroll
            for (int k = 0; k < 8; k++) {
                float4 f = row[k];
                if (i == 0) {
                    acc[k * 4 + 0] = f.x; acc[k * 4 + 1] = f.y;
                    acc[k * 4 + 2] = f.z; acc[k * 4 + 3] = f.w;
                } else {
                    acc[k * 4 + 0] += f.x; acc[k * 4 + 1] += f.y;
                    acc[k * 4 + 2] += f.z; acc[k * 4 + 3] += f.w;
                }
            }
        }
        #pragma unroll
        for (int e = 0; e < 32; e++) outp[st * 32 + e] = sigm(acc[e]);
    }
}

// ---------------------------------------------------------------------------
// K2: dist[b][j] = mean over t of emb[b][t][j]
// ---------------------------------------------------------------------------
__global__ __launch_bounds__(256) void k_dist(const float* __restrict__ emb,
                                              float* __restrict__ dist)
{
    int b = blockIdx.x;
    int j = threadIdx.x & 63;
    int grp = threadIdx.x >> 6;
    float s = 0.f;
    for (int t = grp; t < SS; t += 4) s += emb[((size_t)b * SS + t) * INS + j];
    __shared__ float red[4][64];
    red[grp][j] = s;
    __syncthreads();
    if (grp == 0)
        dist[b * 64 + j] = (red[0][j] + red[1][j] + red[2][j] + red[3][j]) * (1.f / SS);
}

// ---------------------------------------------------------------------------
// K_XW: xw[row][tid] = pack2(g0-row dot x + biases, g1-row dot x + biases)
// ---------------------------------------------------------------------------
#define XW_ROWS 64
__global__ __launch_bounds__(256) void k_xw(
    const float* __restrict__ emb, const float* __restrict__ Wih,
    const float* __restrict__ bih, const float* __restrict__ bhh,
    half2v* __restrict__ xwv)      // [row][256] half2v
{
    int tid = threadIdx.x;
    size_t r0 = (size_t)blockIdx.x * XW_ROWS;
    int u, g0, g1; bool lo;
    gate_map(tid, u, lo, g0, g1);

    half2v wa[32], wb[32];
    const float* pa_ = Wih + (size_t)g0 * INS;
    const float* pb_ = Wih + (size_t)g1 * INS;
    #pragma unroll
    for (int i = 0; i < 32; i++) {
        wa[i] = pack2(pa_[2 * i], pa_[2 * i + 1]);
        wb[i] = pack2(pb_[2 * i], pb_[2 * i + 1]);
    }
    float ba = bih[g0] + bhh[g0], bb = bih[g1] + bhh[g1];

    __shared__ alignas(16) half2v xsh[XW_ROWS * 32];   // 8 KiB
    const float4* src = (const float4*)(emb + r0 * INS);
    #pragma unroll
    for (int k = 0; k < 4; k++) {
        int fi = k * 256 + tid;
        float4 v = src[fi];
        xsh[fi * 2]     = pack2(v.x, v.y);
        xsh[fi * 2 + 1] = pack2(v.z, v.w);
    }
    __syncthreads();

    #pragma unroll 2
    for (int r = 0; r < XW_ROWS; r++) {
        const half8* xr8 = (const half8*)&xsh[r * 32];
        h8u x8[8];
        #pragma unroll
        for (int k = 0; k < 8; k++) x8[k].v = xr8[k];   // 8 x ds_read_b128
        float a0 = 0.f, a1 = 0.f, b0 = 0.f, b1 = 0.f;
        #pragma unroll
        for (int i = 0; i < 32; i += 2) {
            half2v x0 = x8[i >> 2].p[i & 3], x1 = x8[(i + 1) >> 2].p[(i + 1) & 3];
            a0 = fdot2f(x0, wa[i], a0);
            a1 = fdot2f(x1, wa[i + 1], a1);
            b0 = fdot2f(x0, wb[i], b0);
            b1 = fdot2f(x1, wb[i + 1], b1);
        }
        xwv[(r0 + r) * 256 + tid] = pack2(ba + a0 + a1, bb + b0 + b1);
    }
}

// ---------------------------------------------------------------------------
// K3: LSTM (R8 structure) with VALU permlane32_swap exchanges (was shfl_xor/
// ds_bpermute): removes ~3x60cy of LDS-pipe latency from the serial tail.
// ---------------------------------------------------------------------------
__global__ __launch_bounds__(256, 1) void k_lstm9(
    const half2v* __restrict__ xw, const float* __restrict__ h0,
    const float* __restrict__ c0, const float* __restrict__ Whh,
    float* __restrict__ hfin)
{
    int b = blockIdx.x;
    int tid = threadIdx.x;
    int u, g0_, g1_; bool lo;
    gate_map(tid, u, lo, g0_, g1_);
    int koff = lo ? 0 : 64;        // my K-half (f16 elements)

    // all 4 gate rows of unit u, my K-half: 4 x 32 half2v = 128 VGPRs
    half2v wI[32], wF[32], wG[32], wO[32];
    {
        const float* rI = Whh + (size_t)(u)       * HS + koff;
        const float* rF = Whh + (size_t)(128 + u) * HS + koff;
        const float* rG = Whh + (size_t)(256 + u) * HS + koff;
        const float* rO = Whh + (size_t)(384 + u) * HS + koff;
        #pragma unroll
        for (int i = 0; i < 32; i++) {
            wI[i] = pack2(rI[2 * i], rI[2 * i + 1]);
            wF[i] = pack2(rF[2 * i], rF[2 * i + 1]);
            wG[i] = pack2(rG[2 * i], rG[2 * i + 1]);
            wO[i] = pack2(rO[2 * i], rO[2 * i + 1]);
        }
    }

    __shared__ alignas(16) _Float16 hsh[2][HS];
    float c = 0.f, h = 0.f;
    if (!lo) c = c0[b * HS + u];               // hi lanes own the c state
    if (tid < 128) hsh[0][tid] = (_Float16)h0[b * HS + tid];
    __syncthreads();

    const half2v* xwrow = xw + (size_t)b * SS * 256 + tid;
    half2v xb0 = xwrow[0];
    half2v xb1 = xwrow[256];
    half2v xb2 = xwrow[512];
    half2v xb3 = xwrow[768];

// one LSTM step. XB: xw(t) prefetch reg (reloaded for t+4 -> 4-step distance);
// RB: compile-time LDS h buffer index.
#define LSTEP(XB, RB, TN)                                                      \
    {                                                                          \
        const half8* hb8 = (const half8*)(&hsh[RB][0] + koff);                 \
        h8u h8[8];                                                             \
        _Pragma("unroll")                                                      \
        for (int k_ = 0; k_ < 8; k_++) h8[k_].v = hb8[k_];  /* 8x b128 */      \
        float pIa = 0.f, pFa = 0.f, pGa = 0.f, pOa = 0.f;                      \
        float pIb = 0.f, pFb = 0.f, pGb = 0.f, pOb = 0.f;                      \
        _Pragma("unroll")                                                      \
        for (int j_ = 0; j_ < 16; j_++) {                                      \
            half2v hv = h8[j_ >> 2].p[j_ & 3];                                 \
            pIa = fdot2f(hv, wI[j_], pIa);                                     \
            pFa = fdot2f(hv, wF[j_], pFa);                                     \
            pGa = fdot2f(hv, wG[j_], pGa);                                     \
            pOa = fdot2f(hv, wO[j_], pOa);                                     \
        }                                                                      \
        _Pragma("unroll")                                                      \
        for (int j_ = 16; j_ < 32; j_++) {                                     \
            half2v hv = h8[j_ >> 2].p[j_ & 3];                                 \
            pIb = fdot2f(hv, wI[j_], pIb);                                     \
            pFb = fdot2f(hv, wF[j_], pFb);                                     \
            pGb = fdot2f(hv, wG[j_], pGb);                                     \
            pOb = fdot2f(hv, wO[j_], pOb);                                     \
        }                                                                      \
        float pI = pIa + pIb, pF = pFa + pFb;                                  \
        float pG = pGa + pGb, pO = pOa + pOb;                                  \
        float r1 = pswap32(lo ? pF : pI, lo);   /* lo: pI_hi | hi: pF_lo */    \
        float r2 = pswap32(lo ? pO : pG, lo);   /* lo: pG_hi | hi: pO_lo */    \
        float pre0 = (lo ? pI : pF) + r1 + (float)XB.x;                        \
        float pre1 = (lo ? pG : pO) + r2 + (float)XB.y;                        \
        float act0 = sigm(pre0);                    /* lo: i | hi: f */        \
        float act1 = lo ? ftanh(pre1) : sigm(pre1); /* lo: g | hi: o */        \
        float pig = pswap32(act0 * act1, lo);   /* hi receives i*g */          \
        if (!lo) {                                                             \
            c = __builtin_fmaf(act0, c, pig);                                  \
            h = act1 * ftanh(c);                                               \
            hsh[RB ^ 1][u] = (_Float16)h;                                      \
        }                                                                      \
        {                                                                      \
            int tn_ = (TN) < SS ? (TN) : (SS - 1);                             \
            XB = xwrow[(size_t)tn_ * 256];                                     \
        }                                                                      \
        asm volatile("s_waitcnt lgkmcnt(0)" ::: "memory");                     \
        __builtin_amdgcn_s_barrier();                                          \
        __builtin_amdgcn_sched_barrier(0);                                     \
    }

    for (int t = 0; t < SS; t += 4) {
        LSTEP(xb0, 0, t + 4)
        LSTEP(xb1, 1, t + 5)
        LSTEP(xb2, 0, t + 6)
        LSTEP(xb3, 1, t + 7)
    }
#undef LSTEP

    if (!lo) hfin[b * HS + u] = h;
}

// ---------------------------------------------------------------------------
// K3 (fallback, ws too small for xW)
// ---------------------------------------------------------------------------
__global__ __launch_bounds__(256, 1) void k_lstm_fb(
    const float* __restrict__ emb, const float* __restrict__ h0,
    const float* __restrict__ c0, const float* __restrict__ Wih,
    const float* __restrict__ Whh, const float* __restrict__ bih,
    const float* __restrict__ bhh, float* __restrict__ hfin)
{
    int b = blockIdx.x;
    int tid = threadIdx.x;

    half2v wih[2][32], whh[2][64];
    #pragma unroll
    for (int g = 0; g < 2; g++) {
        int gg = tid + g * 256;
        const float* wr = Wih + (size_t)gg * INS;
        #pragma unroll
        for (int i = 0; i < 32; i++) wih[g][i] = pack2(wr[2 * i], wr[2 * i + 1]);
        const float* hr = Whh + (size_t)gg * HS;
        #pragma unroll
        for (int i = 0; i < 64; i++) whh[g][i] = pack2(hr[2 * i], hr[2 * i + 1]);
    }
    float bias0 = bih[tid] + bhh[tid];
    float bias1 = bih[tid + 256] + bhh[tid + 256];

    __shared__ alignas(16) half2v xh[96];
    __shared__ float f_act[128], o_act[128];
    __shared__ float xf[64], hf[128];

    float c = 0.f, h = 0.f;
    if (tid < 128) c = c0[b * HS + tid];

    const float* xrow = emb + (size_t)b * SS * INS;
    if (tid < 64) xf[tid] = xrow[tid];
    if (tid < 128) hf[tid] = h0[b * HS + tid];
    __syncthreads();
    if (tid < 32) xh[tid] = pack2(xf[2 * tid], xf[2 * tid + 1]);
    else if (tid < 96) { int uu = tid - 32; xh[tid] = pack2(hf[2 * uu], hf[2 * uu + 1]); }
    __syncthreads();

    for (int t = 0; t < SS; t++) {
        float xn = 0.f;
        if (tid >= 128 && tid < 192 && t + 1 < SS) xn = xrow[(size_t)(t + 1) * INS + (tid - 128)];

        float a0a = 0.f, a0b = 0.f, a1a = 0.f, a1b = 0.f;
        #pragma unroll
        for (int i = 0; i < 32; i += 2) {
            half2v x0 = xh[i], x1 = xh[i + 1];
            a0a = fdot2f(x0, wih[0][i], a0a);
            a0b = fdot2f(x1, wih[0][i + 1], a0b);
            a1a = fdot2f(x0, wih[1][i], a1a);
            a1b = fdot2f(x1, wih[1][i + 1], a1b);
        }
        #pragma unroll
        for (int i = 0; i < 64; i += 2) {
            half2v h0v = xh[32 + i], h1v = xh[32 + i + 1];
            a0a = fdot2f(h0v, whh[0][i], a0a);
            a0b = fdot2f(h1v, whh[0][i + 1], a0b);
            a1a = fdot2f(h0v, whh[1][i], a1a);
            a1b = fdot2f(h1v, whh[1][i + 1], a1b);
        }
        float a0 = bias0 + a0a + a0b;
        float a1 = bias1 + a1a + a1b;

        float iact = 0.f, gact = 0.f;
        if (tid < 128) { iact = sigm(a0); gact = ftanh(a1); }
        else           { f_act[tid - 128] = sigm(a0); o_act[tid - 128] = sigm(a1); }
        __syncthreads();

        if (tid < 128) {
            c = f_act[tid] * c + iact * gact;
            h = o_act[tid] * ftanh(c);
            hf[tid] = h;
        } else if (tid < 192) {
            xf[tid - 128] = xn;
        }
        __syncthreads();

        if (tid < 32) xh[tid] = pack2(xf[2 * tid], xf[2 * tid + 1]);
        else if (tid < 96) { int uu = tid - 32; xh[tid] = pack2(hf[2 * uu], hf[2 * uu + 1]); }
        __syncthreads();
    }
    if (tid < 128) hfin[b * HS + tid] = h;
}

// ---------------------------------------------------------------------------
// K4: decoder logits + T=1e-3 softmax + freq-rec head. one block per b.
// ---------------------------------------------------------------------------
__global__ __launch_bounds__(256) void k_head(
    const float* __restrict__ hfin, const float* __restrict__ decW,
    const float* __restrict__ decB, const float* __restrict__ ad_emb,
    const float* __restrict__ encW, const float* __restrict__ encB,
    const float* __restrict__ dist, const float* __restrict__ fc1W,
    const float* __restrict__ fc1b, const float* __restrict__ fc2W,
    const float* __restrict__ fc2b, float* __restrict__ outp)
{
    int b = blockIdx.x;
    int tid = threadIdx.x;
    __shared__ alignas(16) float hsh[128];
    __shared__ float logit_s[4][256];
    __shared__ float probs_s[4][256];
    __shared__ float be_s[128];
    __shared__ float fe_dist[96];
    __shared__ float fr1[10];

    if (tid < 128) hsh[tid] = hfin[b * HS + tid];
    __syncthreads();

    {
        f32x4 hv[32];
        const f32x4* h4 = (const f32x4*)hsh;
        #pragma unroll
        for (int j = 0; j < 32; j++) hv[j] = h4[j];
        #pragma unroll
        for (int k = 0; k < 4; k++) {
            const float4* w4 = (const float4*)(decW + ((size_t)k * OUTS + tid) * HS);
            float a0 = decB[k * OUTS + tid], a1 = 0.f;
            #pragma unroll
            for (int j = 0; j < 32; j++) {
                float4 wv = w4[j];
                a0 = __builtin_fmaf(hv[j][0], wv.x, a0);
                a1 = __builtin_fmaf(hv[j][1], wv.y, a1);
                a0 = __builtin_fmaf(hv[j][2], wv.z, a0);
                a1 = __builtin_fmaf(hv[j][3], wv.w, a1);
            }
            float acc = a0 + a1;
            logit_s[k][tid] = acc;
            outp[65536 + k * 16384 + b * 256 + tid] = acc;
        }
    }
    __syncthreads();

    {
        int k = tid >> 6, lane = tid & 63;
        float v0 = logit_s[k][lane],       v1 = logit_s[k][lane + 64];
        float v2 = logit_s[k][lane + 128], v3 = logit_s[k][lane + 192];
        float m = fmaxf(fmaxf(v0, v1), fmaxf(v2, v3));
        for (int off = 32; off; off >>= 1) m = fmaxf(m, __shfl_xor(m, off, 64));
        float e0 = fexp2((v0 - m) * 1442.695041f), e1 = fexp2((v1 - m) * 1442.695041f);
        float e2 = fexp2((v2 - m) * 1442.695041f), e3 = fexp2((v3 - m) * 1442.695041f);
        float s = e0 + e1 + e2 + e3;
        for (int off = 32; off; off >>= 1) s += __shfl_xor(s, off, 64);
        float inv = 1.f / s;
        float p0 = e0 * inv, p1 = e1 * inv, p2 = e2 * inv, p3 = e3 * inv;
        probs_s[k][lane] = p0;        probs_s[k][lane + 64] = p1;
        probs_s[k][lane + 128] = p2;  probs_s[k][lane + 192] = p3;
        outp[k * 16384 + b * 256 + lane] = p0;
        outp[k * 16384 + b * 256 + lane + 64] = p1;
        outp[k * 16384 + b * 256 + lane + 128] = p2;
        outp[k * 16384 + b * 256 + lane + 192] = p3;
    }
    __syncthreads();

    if (tid < 128) {
        int k = tid >> 5, e = tid & 31;
        const float* te = ad_emb + (size_t)k * OUTS * EMBS + e;
        float acc = 0.f;
        #pragma unroll 8
        for (int o = 0; o < OUTS; o++) acc += probs_s[k][o] * te[o * EMBS];
        be_s[tid] = acc;
    }
    __syncthreads();

    if (tid < 32) {
        const float* w = encW + tid * 128;
        float acc = encB[tid];
        #pragma unroll 8
        for (int kk = 0; kk < 128; kk++) acc += be_s[kk] * w[kk];
        fe_dist[tid] = sigm(acc);
    } else if (tid < 96) {
        fe_dist[tid] = dist[b * 64 + (tid - 32)];
    }
    __syncthreads();

    if (tid < 10) {
        float acc = fc1b[tid];
        for (int kk = 0; kk < 96; kk++) acc += fe_dist[kk] * fc1W[tid * 96 + kk];
        fr1[tid] = fmaxf(acc, 0.f);
    }
    __syncthreads();

    if (tid < 2) {
        float acc = fc2b[tid];
        for (int kk = 0; kk < 10; kk++) acc += fr1[kk] * fc2W[tid * 10 + kk];
        outp[131072 + tid * 64 + b] = sigm(acc);
    }
}

// ---------------------------------------------------------------------------
extern "C" void kernel_launch(void* const* d_in, const int* in_sizes, int n_in,
                              void* d_out, int out_size, void* d_ws, size_t ws_size,
                              hipStream_t stream)
{
    const int*   inp    = (const int*)d_in[0];
    const float* h0     = (const float*)d_in[1];
    const float* c0     = (const float*)d_in[2];
    const float* pc_emb = (const float*)d_in[3];
    const float* ad_emb = (const float*)d_in[4];
    const float* encW   = (const float*)d_in[5];
    const float* encB   = (const float*)d_in[6];
    const float* Wih    = (const float*)d_in[7];
    const float* Whh    = (const float*)d_in[8];
    const float* bih    = (const float*)d_in[9];
    const float* bhh    = (const float*)d_in[10];
    const float* decW   = (const float*)d_in[11];
    const float* decB   = (const float*)d_in[12];
    const float* fc1W   = (const float*)d_in[13];
    const float* fc1b   = (const float*)d_in[14];
    const float* fc2W   = (const float*)d_in[15];
    const float* fc2b   = (const float*)d_in[16];

    if (ws_size < WS_SMALL * 4ull) return;

    float* ws   = (float*)d_ws;
    float* emb  = ws;
    float* dist = ws + WS_DIST;
    float* hfin = ws + WS_HFIN;
    float* P    = ws + WS_P;
    float* outp = (float*)d_out;
    bool big = (ws_size >= WS_BIG * 4ull);

    hipLaunchKernelGGL(k_pre, dim3(256), dim3(256), 0, stream,
                       pc_emb, ad_emb, encW, encB, P);
    hipLaunchKernelGGL(k_embed2, dim3(512), dim3(256), 0, stream,
                       inp, P, emb);
    hipLaunchKernelGGL(k_dist, dim3(64), dim3(256), 0, stream, emb, dist);
    if (big) {
        half2v* xwv = (half2v*)(ws + WS_XW);
        hipLaunchKernelGGL(k_xw, dim3(BS * SS / XW_ROWS), dim3(256), 0, stream,
                           emb, Wih, bih, bhh, xwv);
        hipLaunchKernelGGL(k_lstm9, dim3(64), dim3(256), 0, stream,
                           xwv, h0, c0, Whh, hfin);
    } else {
        hipLaunchKernelGGL(k_lstm_fb, dim3(64), dim3(256), 0, stream,
                           emb, h0, c0, Wih, Whh, bih, bhh, hfin);
    }
    hipLaunchKernelGGL(k_head, dim3(64), dim3(256), 0, stream,
                       hfin, decW, decB, ad_emb, encW, encB, dist,
                       fc1W, fc1b, fc2W, fc2b, outp);
}